// Round 7
// baseline (111.295 us; speedup 1.0000x reference)
//
#include <hip/hip_runtime.h>

#define RADIUS 8
#define N 512
#define TR 32                   // rows per strip
#define SPB 2                   // strips per block (register-carried halo)
#define LSTRIDE 516             // dwords; %4==0 → 16B-aligned rows for ds_read_b128

__global__ __launch_bounds__(512, 4)
void box_kernel(const float* __restrict__ in, float* __restrict__ out) {
    __shared__ __align__(16) float tile[TR * LSTRIDE];   // 66,048 B → 2 blocks/CU

    const int blk   = blockIdx.x;
    const int img   = blk >> 3;            // 8 groups of 64 rows per image
    const int grp   = blk & 7;
    const int rbase = grp * (TR * SPB);    // first output row of this block
    const float* __restrict__ ibase = in  + (size_t)img * N * N;
    float* __restrict__       obase = out + (size_t)img * N * N;
    const int t = threadIdx.x;

    // ---- Single up-front burst: ALL 80 window rows (outputs rbase..rbase+63)
    // as one run of independent loads — max memory-level parallelism, and the
    // interior 16-row halo between the two strips is read ONCE (1.25× vs 1.5×).
    float x[80];
    {
        const int c = t;                   // column 0..511
#pragma unroll
        for (int k = 0; k < 80; ++k) {
            const int row = rbase + k - RADIUS;
            x[k] = (row >= 0 && row < N) ? ibase[(size_t)row * N + c] : 0.0f;
        }
    }

    const int qid  = t & 127;              // phase-2: col-quad 0..127
    const int rgrp = t >> 7;               // phase-2: row-group 0..3
    const int q0   = qid * 4;

#pragma unroll
    for (int s = 0; s < SPB; ++s) {        // fully static after unroll
        const int b  = TR * s;             // window base in x[]
        const int r0 = rbase + TR * s;

        // ---- Phase 1: vertical 17-tap sliding sum from registers → LDS.
        // (strip 1 issues ZERO global loads — pure VALU+LDS, hides under
        //  the other resident block's memory phase)
        {
            const int c = t;
            float vs = 0.0f;
#pragma unroll
            for (int k = 0; k <= 2 * RADIUS; ++k) vs += x[b + k];
#pragma unroll
            for (int i = 0; i < TR; ++i) {
                tile[i * LSTRIDE + c] = vs;
                if (i + 1 < TR) vs += x[b + i + 2 * RADIUS + 1] - x[b + i];
            }
        }
        __syncthreads();

        // ---- Phase 2: horizontal 17-tap sum; 5 aligned ds_read_b128 per row;
        // wave = 64 consecutive quads on ONE row → 1 KB contiguous stores.
#pragma unroll
        for (int i = 0; i < 8; ++i) {
            const int r = rgrp * 8 + i;
            const float* trow = &tile[r * LSTRIDE];
            float wv[20];                  // window cols q0-8 .. q0+11 (OOB → 0)
#pragma unroll
            for (int p = 0; p < 5; ++p) {
                const int cs = q0 - 8 + 4 * p;        // ≡ 0 mod 4
                float4 vv = (cs >= 0 && cs < N)
                          ? *reinterpret_cast<const float4*>(trow + cs)
                          : make_float4(0.0f, 0.0f, 0.0f, 0.0f);
                wv[4 * p + 0] = vv.x; wv[4 * p + 1] = vv.y;
                wv[4 * p + 2] = vv.z; wv[4 * p + 3] = vv.w;
            }
            float sum = 0.0f;
#pragma unroll
            for (int k = 0; k < 17; ++k) sum += wv[k];
            const float o0 = sum;
            const float o1 = o0 - wv[0] + wv[17];
            const float o2 = o1 - wv[1] + wv[18];
            const float o3 = o2 - wv[2] + wv[19];
            *reinterpret_cast<float4*>(obase + (size_t)(r0 + r) * N + q0) =
                make_float4(o0, o1, o2, o3);
        }

        if (s + 1 < SPB) __syncthreads();  // P2 reads done before next P1 overwrite
    }
}

extern "C" void kernel_launch(void* const* d_in, const int* in_sizes, int n_in,
                              void* d_out, int out_size, void* d_ws, size_t ws_size,
                              hipStream_t stream) {
    const float* in = (const float*)d_in[0];
    float* out = (float*)d_out;
    dim3 grid(8 * 32 * (N / (TR * SPB)));  // 2048 blocks
    dim3 block(512);
    hipLaunchKernelGGL(box_kernel, grid, block, 0, stream, in, out);
}

// Round 8
// 109.726 us; speedup vs baseline: 1.0143x; 1.0143x over previous
//
#include <hip/hip_runtime.h>

#define RADIUS 8
#define N 512
#define TR 32                   // rows per strip
#define HALF 256                // rows per block (half image)
#define NSTRIP (HALF / TR)      // 8 strips
#define LSTRIDE 516             // dwords; %4==0 → 16B-aligned rows for ds_read_b128

__global__ __launch_bounds__(512, 4)
void box_kernel(const float* __restrict__ in, float* __restrict__ out) {
    __shared__ __align__(16) float tile[TR * LSTRIDE];   // 66,048 B → 2 blocks/CU

    const int blk   = blockIdx.x;
    const int img   = blk >> 1;
    const int half  = blk & 1;
    const int rbase = half * HALF;
    const float* __restrict__ ibase = in  + (size_t)img * N * N;
    float* __restrict__       obase = out + (size_t)img * N * N;
    const int t = threadIdx.x;
    const int c = t;                       // phase-1 column

    // Initial burst: strip-0 window rows [rbase-8, rbase+40) — 48 independent
    // loads (max MLP). Between strips we carry the 16-row overlap in registers
    // and burst only 32 fresh rows → per-block reads = 272 rows / 256 outputs.
    float x[48];
#pragma unroll
    for (int k = 0; k < 48; ++k) {
        const int row = rbase + k - RADIUS;
        x[k] = (row >= 0 && row < N) ? ibase[(size_t)row * N + c] : 0.0f;
    }

    const int qid  = t & 127;              // phase-2: col-quad 0..127
    const int rgrp = t >> 7;               // phase-2: row-group 0..3
    const int q0   = qid * 4;

#pragma unroll
    for (int s = 0; s < NSTRIP; ++s) {
        const int r0 = rbase + s * TR;

        // ---- Phase 1: vertical 17-tap sliding sum from registers → LDS.
        {
            float vs = 0.0f;
#pragma unroll
            for (int k = 0; k <= 2 * RADIUS; ++k) vs += x[k];
#pragma unroll
            for (int i = 0; i < TR; ++i) {
                tile[i * LSTRIDE + c] = vs;
                if (i + 1 < TR) vs += x[i + 2 * RADIUS + 1] - x[i];
            }
        }
        __syncthreads();

        // ---- Carry halo + prefetch next strip's 32 fresh rows NOW, so the
        // loads are in flight underneath phase-2's LDS reads + compute.
        if (s + 1 < NSTRIP) {
#pragma unroll
            for (int k = 0; k < 16; ++k) x[k] = x[32 + k];   // rows [r0+24, r0+40)
#pragma unroll
            for (int k = 0; k < 32; ++k) {
                const int row = r0 + TR + RADIUS + k;        // rows [r0+40, r0+72), ≥0 always
                x[16 + k] = (row < N) ? ibase[(size_t)row * N + c] : 0.0f;
            }
        }

        // ---- Phase 2: horizontal 17-tap sum; 5 aligned ds_read_b128 per row;
        // wave = 64 consecutive quads on ONE row → 1 KB contiguous stores.
#pragma unroll
        for (int i = 0; i < 8; ++i) {
            const int r = rgrp * 8 + i;
            const float* trow = &tile[r * LSTRIDE];
            float wv[20];                  // window cols q0-8 .. q0+11 (OOB → 0)
#pragma unroll
            for (int p = 0; p < 5; ++p) {
                const int cs = q0 - 8 + 4 * p;               // ≡ 0 mod 4
                float4 vv = (cs >= 0 && cs < N)
                          ? *reinterpret_cast<const float4*>(trow + cs)
                          : make_float4(0.0f, 0.0f, 0.0f, 0.0f);
                wv[4 * p + 0] = vv.x; wv[4 * p + 1] = vv.y;
                wv[4 * p + 2] = vv.z; wv[4 * p + 3] = vv.w;
            }
            float sum = 0.0f;
#pragma unroll
            for (int k = 0; k < 17; ++k) sum += wv[k];
            const float o0 = sum;
            const float o1 = o0 - wv[0] + wv[17];
            const float o2 = o1 - wv[1] + wv[18];
            const float o3 = o2 - wv[2] + wv[19];
            *reinterpret_cast<float4*>(obase + (size_t)(r0 + r) * N + q0) =
                make_float4(o0, o1, o2, o3);
        }

        if (s + 1 < NSTRIP) __syncthreads();   // P2 reads done before next P1 overwrite
    }
}

extern "C" void kernel_launch(void* const* d_in, const int* in_sizes, int n_in,
                              void* d_out, int out_size, void* d_ws, size_t ws_size,
                              hipStream_t stream) {
    const float* in = (const float*)d_in[0];
    float* out = (float*)d_out;
    dim3 grid(8 * 32 * (N / HALF));        // 512 blocks = exactly 2 resident/CU
    dim3 block(512);
    hipLaunchKernelGGL(box_kernel, grid, block, 0, stream, in, out);
}